// Round 4
// baseline (185259.351 us; speedup 1.0000x reference)
//
#include <hip/hip_runtime.h>
#include <math.h>

#define TSTEPS 512
#define NBATCH 256
#define DLL 300
#define DAA 74
#define DVV 35
#define DX  409
#define DH  128
#define DMEM 256
#define CST 768   // 6*DH

typedef unsigned short u16;
typedef unsigned int   u32;
typedef float v2f __attribute__((ext_vector_type(2)));

__device__ __forceinline__ float ulo(u32 u){ return __uint_as_float(u<<16); }
__device__ __forceinline__ float uhi(u32 u){ return __uint_as_float(u & 0xffff0000u); }
__device__ __forceinline__ float sigf(float x){ return 1.0f/(1.0f+expf(-x)); }

// dst[k*OUT + o] = bf16(src[o*IN + k])   (transpose to [K][OUT] for coalesced GEMV)
__global__ void cast_transpose(const float* __restrict__ src, u16* __restrict__ dst,
                               int OUT, int IN){
  int idx = blockIdx.x*blockDim.x + threadIdx.x;
  int total = OUT*IN;
  if (idx >= total) return;
  int k = idx / OUT;
  int o = idx - k*OUT;
  float v = src[o*IN + k];
  u32 u = __float_as_uint(v);
  u32 r = (u + 0x7fffu + ((u>>16)&1u)) >> 16;   // RNE
  dst[idx] = (u16)r;
}

// acc.{x,y} += sum_k act[k] * W[k][2*col+{0,1}]; 2-wide, minimal register footprint.
// Requires ks even (all call sites guarantee); ke may be odd (scalar tail).
template<int OUTh>
__device__ __forceinline__ void gemv2w(const u16* __restrict__ w, const float* __restrict__ act,
                                       int ks, int ke, int col, v2f &acc){
  const u32* __restrict__ wp = (const u32*)w + (size_t)ks*OUTh + col;
  int k = ks;
  for (; k+1<ke; k+=2){
    v2f a = *(const v2f*)&act[k];
    u32 u0 = wp[0], u1 = wp[OUTh];
    wp += 2*OUTh;
    acc.x += a.x*ulo(u0); acc.y += a.x*uhi(u0);
    acc.x += a.y*ulo(u1); acc.y += a.y*uhi(u1);
  }
  if (k < ke){
    u32 u = *wp;
    acc.x += act[k]*ulo(u); acc.y += act[k]*uhi(u);
  }
}

struct P {
  const float* x;
  const float *bih_l,*bhh_l,*bih_a,*bhh_a,*bih_v,*bhh_v;
  const float *a1b1,*a1b2,*a2b1,*a2b2,*g1b1,*g1b2,*g2b1,*g2b2;
  const float *ob1,*ow2,*ob2;
  const u16 *ihl,*hhl,*iha,*hha,*ihv,*hhv;
  const u16 *a1w1,*a1w2,*a2w1,*a2w2,*g1w1,*g1w2,*g2w1,*g2w2,*ow1;
  float* out;
};

__global__ void __launch_bounds__(1024)
__attribute__((amdgpu_waves_per_eu(4)))
mfn_persistent(P p){
  __shared__ __align__(16) float s_x[420];     // l:[0,300) a:[304,378) v:[384,419)
  __shared__ __align__(16) float s_hl[DH], s_ha[DH], s_hv[DH];
  __shared__ __align__(16) float s_cl[DH], s_ca[DH], s_cv[DH];
  __shared__ __align__(16) float s_mem[DMEM];
  __shared__ __align__(16) float s_cstar[CST];
  __shared__ __align__(16) float s_att[1024];  // [0,768)=attended, [768,1024)=mem copy
  __shared__ __align__(16) float s_z[CST];
  __shared__ __align__(16) float s_part[6144]; // A=0, B=2048, C=4096
  __shared__ __align__(16) float s_last[640];
  __shared__ float s_red[4];

  const int tid = threadIdx.x;
  const int n   = blockIdx.x;
  const int g4 = tid>>8, c4 = tid&255;
  const int g8 = tid>>7, c8 = tid&127;

  if (tid < DH){ s_hl[tid]=0.f; s_ha[tid]=0.f; s_hv[tid]=0.f;
                 s_cl[tid]=0.f; s_ca[tid]=0.f; s_cv[tid]=0.f; }
  if (tid < DMEM) s_mem[tid]=0.f;
  if (tid < DX){
    int dst = tid + (tid>=DLL?4:0) + (tid>=DLL+DAA?6:0);
    s_x[dst] = p.x[(size_t)n*DX + tid];
  }
  __syncthreads();

  for (int t=0; t<TSTEPS; t++){
    // ---- phase 1: 3 LSTM gate partials; one matrix at a time (low reg pressure) ----
    {
      v2f a;
      // L: x-part slices {0,76,152,228,300}, h-part 32/group
      a = (v2f){0.f,0.f};
      gemv2w<256>(p.ihl, s_x,     min(76*g4,300), min(76*(g4+1),300), c4, a);
      gemv2w<256>(p.hhl, s_hl,    32*g4, 32*(g4+1), c4, a);
      *(v2f*)&s_part[       g4*512 + 2*c4] = a;
      // A: x slices {0,20,40,60,74}
      a = (v2f){0.f,0.f};
      gemv2w<256>(p.iha, s_x+304, min(20*g4,74), min(20*(g4+1),74), c4, a);
      gemv2w<256>(p.hha, s_ha,    32*g4, 32*(g4+1), c4, a);
      *(v2f*)&s_part[2048 + g4*512 + 2*c4] = a;
      // V: x slices {0,10,20,30,35}
      a = (v2f){0.f,0.f};
      gemv2w<256>(p.ihv, s_x+384, min(10*g4,35), min(10*(g4+1),35), c4, a);
      gemv2w<256>(p.hhv, s_hv,    32*g4, 32*(g4+1), c4, a);
      *(v2f*)&s_part[4096 + g4*512 + 2*c4] = a;
    }
    __syncthreads();                                   // B0

    // ---- LSTM reduce + activations (tid<384: modality m, unit j) ----
    if (tid < 384){
      int m = tid>>7, j = tid&127;
      const float *bi, *bh, *pb; float *sh, *sc;
      if (m==0){ bi=p.bih_l; bh=p.bhh_l; sh=s_hl; sc=s_cl; pb=s_part; }
      else if (m==1){ bi=p.bih_a; bh=p.bhh_a; sh=s_ha; sc=s_ca; pb=s_part+2048; }
      else { bi=p.bih_v; bh=p.bhh_v; sh=s_hv; sc=s_cv; pb=s_part+4096; }
      float g0,g1,g2,g3;
      g0 = bi[j]     +bh[j]      + pb[j]      +pb[512+j]      +pb[1024+j]      +pb[1536+j];
      g1 = bi[128+j] +bh[128+j]  + pb[128+j]  +pb[512+128+j]  +pb[1024+128+j]  +pb[1536+128+j];
      g2 = bi[256+j] +bh[256+j]  + pb[256+j]  +pb[512+256+j]  +pb[1024+256+j]  +pb[1536+256+j];
      g3 = bi[384+j] +bh[384+j]  + pb[384+j]  +pb[512+384+j]  +pb[1024+384+j]  +pb[1536+384+j];
      float ig=sigf(g0), fg=sigf(g1), gg=tanhf(g2), og=sigf(g3);
      float c_old = sc[j];
      float c = fg*c_old + ig*gg;
      float h = og*tanhf(c);
      s_cstar[tid]     = c_old;
      s_cstar[384+tid] = c;
      sc[j]=c; sh[j]=h;
    }
    __syncthreads();                                   // B1

    // ---- att1_W1: (256,768) partials ----
    {
      v2f a = (v2f){0.f,0.f};
      gemv2w<128>(p.a1w1, s_cstar, 96*g8, 96*(g8+1), c8, a);
      *(v2f*)&s_part[g8*256 + 2*c8] = a;
    }
    __syncthreads();                                   // B2
    if (tid < 256){
      float z = p.a1b1[tid];
      z += s_part[tid]       + s_part[256+tid]  + s_part[512+tid]  + s_part[768+tid];
      z += s_part[1024+tid]  + s_part[1280+tid] + s_part[1536+tid] + s_part[1792+tid];
      s_z[tid] = fmaxf(z, 0.f);
    }
    __syncthreads();                                   // B3

    // ---- att1_W2: (768,256) partials (768 active threads) ----
    if (tid < 768){
      int g2i = (tid >= 384) ? 1 : 0;
      int c   = tid - 384*g2i;
      v2f a = (v2f){0.f,0.f};
      gemv2w<384>(p.a1w2, s_z, 128*g2i, 128*(g2i+1), c, a);
      *(v2f*)&s_part[g2i*768 + 2*c] = a;
    }
    __syncthreads();                                   // B4

    // ---- softmax over 768 + attended; mem copied into s_att[768:1024) ----
    {
      float sc0=-1e30f, sc1=-1e30f, sc2=-1e30f;
      if (tid < 256){
        sc0 = p.a1b2[tid]     + s_part[tid]     + s_part[768+tid];
        sc1 = p.a1b2[tid+256] + s_part[256+tid] + s_part[1024+tid];
        sc2 = p.a1b2[tid+512] + s_part[512+tid] + s_part[1280+tid];
      }
      float m = fmaxf(fmaxf(sc0,sc1),sc2);
      for (int off=32; off; off>>=1) m = fmaxf(m, __shfl_down(m, off));
      if (tid < 256 && (tid&63)==0) s_red[tid>>6]=m;
      __syncthreads();                                 // B5
      m = fmaxf(fmaxf(s_red[0],s_red[1]), fmaxf(s_red[2],s_red[3]));
      float e0=expf(sc0-m), e1=expf(sc1-m), e2=expf(sc2-m);
      float s = e0+e1+e2;
      for (int off=32; off; off>>=1) s += __shfl_down(s, off);
      __syncthreads();                                 // B6
      if (tid < 256 && (tid&63)==0) s_red[tid>>6]=s;
      if (tid >= 256 && tid < 512) s_att[512+tid] = s_mem[tid-256];
      __syncthreads();                                 // B7
      float inv = 1.0f/(s_red[0]+s_red[1]+s_red[2]+s_red[3]);
      if (tid < 256){
        s_att[tid]     = e0*inv*s_cstar[tid];
        s_att[tid+256] = e1*inv*s_cstar[tid+256];
        s_att[tid+512] = e2*inv*s_cstar[tid+512];
      }
    }
    __syncthreads();                                   // B8

    // ---- att2 / g1 / g2 layer-1 partials: three sequential thin passes ----
    {
      v2f a;
      a = (v2f){0.f,0.f};
      gemv2w<128>(p.a2w1, s_att, 96*g8, 96*(g8+1), c8, a);       // K=768
      *(v2f*)&s_part[       g8*256 + 2*c8] = a;
      a = (v2f){0.f,0.f};
      gemv2w<128>(p.g1w1, s_att, 128*g8, 128*(g8+1), c8, a);     // K=1024 ([att|mem])
      *(v2f*)&s_part[2048 + g8*256 + 2*c8] = a;
      a = (v2f){0.f,0.f};
      gemv2w<128>(p.g2w1, s_att, 128*g8, 128*(g8+1), c8, a);     // K=1024
      *(v2f*)&s_part[4096 + g8*256 + 2*c8] = a;
    }
    __syncthreads();                                   // B9
    if (tid < 256){
      float u=p.a2b1[tid], v1=p.g1b1[tid], v2=p.g2b1[tid];
      #pragma unroll
      for (int g=0; g<8; g++){
        u  += s_part[g*256 + tid];
        v1 += s_part[2048 + g*256 + tid];
        v2 += s_part[4096 + g*256 + tid];
      }
      s_z[tid]     = fmaxf(u ,0.f);
      s_z[256+tid] = fmaxf(v1,0.f);
      s_z[512+tid] = fmaxf(v2,0.f);
    }
    __syncthreads();                                   // B10

    // ---- layer-2s: cHat / gamma1 / gamma2 partials ----
    {
      v2f a;
      a = (v2f){0.f,0.f};
      gemv2w<128>(p.a2w2, s_z,     32*g8, 32*(g8+1), c8, a);
      *(v2f*)&s_part[       g8*256 + 2*c8] = a;
      a = (v2f){0.f,0.f};
      gemv2w<128>(p.g1w2, s_z+256, 32*g8, 32*(g8+1), c8, a);
      *(v2f*)&s_part[2048 + g8*256 + 2*c8] = a;
      a = (v2f){0.f,0.f};
      gemv2w<128>(p.g2w2, s_z+512, 32*g8, 32*(g8+1), c8, a);
      *(v2f*)&s_part[4096 + g8*256 + 2*c8] = a;
    }
    __syncthreads();                                   // B11
    // reduce + mem update (tid<256); idle threads 512.. prefetch next x row into s_x
    if (tid < 256){
      float ch=p.a2b2[tid], gm1=p.g1b2[tid], gm2=p.g2b2[tid];
      #pragma unroll
      for (int g=0; g<8; g++){
        ch  += s_part[g*256 + tid];
        gm1 += s_part[2048 + g*256 + tid];
        gm2 += s_part[4096 + g*256 + tid];
      }
      ch = tanhf(ch); gm1 = sigf(gm1); gm2 = sigf(gm2);
      s_mem[tid] = gm1*s_mem[tid] + gm2*ch;
    } else if (tid >= 512 && tid-512 < DX && t+1 < TSTEPS){
      int i = tid-512;
      int dst = i + (i>=DLL?4:0) + (i>=DLL+DAA?6:0);
      s_x[dst] = p.x[((size_t)(t+1)*NBATCH + n)*DX + i];
    }
    __syncthreads();                                   // B12
  }

  // ---- output MLP ----
  if (tid < DH){ s_last[tid]=s_hl[tid]; s_last[DH+tid]=s_ha[tid]; s_last[2*DH+tid]=s_hv[tid]; }
  if (tid < DMEM) s_last[3*DH+tid]=s_mem[tid];
  __syncthreads();
  {
    v2f a = (v2f){0.f,0.f};
    gemv2w<128>(p.ow1, s_last, 80*g8, 80*(g8+1), c8, a);
    *(v2f*)&s_part[g8*256 + 2*c8] = a;
  }
  __syncthreads();
  {
    float pp = 0.f;
    if (tid < 256){
      float z = p.ob1[tid];
      #pragma unroll
      for (int g=0; g<8; g++) z += s_part[g*256 + tid];
      pp = fmaxf(z, 0.f) * p.ow2[tid];
    }
    for (int off=32; off; off>>=1) pp += __shfl_down(pp, off);
    if (tid < 256 && (tid&63)==0) s_red[tid>>6]=pp;
    __syncthreads();
    if (tid==0) p.out[n] = s_red[0]+s_red[1]+s_red[2]+s_red[3] + p.ob2[0];
  }
}

extern "C" void kernel_launch(void* const* d_in, const int* in_sizes, int n_in,
                              void* d_out, int out_size, void* d_ws, size_t ws_size,
                              hipStream_t stream){
  u16* ws = (u16*)d_ws;
  struct M { int src; size_t off; int OUT, IN; };
  const M mats[15] = {
    { 5,       0, 512,  300},   // Wih_l
    { 6,  153600, 512,  128},   // Whh_l
    { 9,  219136, 512,   74},   // Wih_a
    {10,  257024, 512,  128},   // Whh_a
    {13,  322560, 512,   35},   // Wih_v
    {14,  340480, 512,  128},   // Whh_v
    {17,  406016, 256,  768},   // att1_W1
    {19,  602624, 768,  256},   // att1_W2
    {21,  799232, 256,  768},   // att2_W1
    {23,  995840, 256,  256},   // att2_W2
    {25, 1061376, 256, 1024},   // g1_W1
    {27, 1323520, 256,  256},   // g1_W2
    {29, 1389056, 256, 1024},   // g2_W1
    {31, 1651200, 256,  256},   // g2_W2
    {33, 1716736, 256,  640},   // out_W1
  };
  for (int i=0;i<15;i++){
    int total = mats[i].OUT*mats[i].IN;
    cast_transpose<<<(total+255)/256, 256, 0, stream>>>(
        (const float*)d_in[mats[i].src], ws + mats[i].off, mats[i].OUT, mats[i].IN);
  }

  P p;
  p.x     = (const float*)d_in[0];
  p.bih_l = (const float*)d_in[7];  p.bhh_l = (const float*)d_in[8];
  p.bih_a = (const float*)d_in[11]; p.bhh_a = (const float*)d_in[12];
  p.bih_v = (const float*)d_in[15]; p.bhh_v = (const float*)d_in[16];
  p.a1b1  = (const float*)d_in[18]; p.a1b2  = (const float*)d_in[20];
  p.a2b1  = (const float*)d_in[22]; p.a2b2  = (const float*)d_in[24];
  p.g1b1  = (const float*)d_in[26]; p.g1b2  = (const float*)d_in[28];
  p.g2b1  = (const float*)d_in[30]; p.g2b2  = (const float*)d_in[32];
  p.ob1   = (const float*)d_in[34]; p.ow2   = (const float*)d_in[35];
  p.ob2   = (const float*)d_in[36];
  p.ihl   = ws + 0;       p.hhl  = ws + 153600;
  p.iha   = ws + 219136;  p.hha  = ws + 257024;
  p.ihv   = ws + 322560;  p.hhv  = ws + 340480;
  p.a1w1  = ws + 406016;  p.a1w2 = ws + 602624;
  p.a2w1  = ws + 799232;  p.a2w2 = ws + 995840;
  p.g1w1  = ws + 1061376; p.g1w2 = ws + 1323520;
  p.g2w1  = ws + 1389056; p.g2w2 = ws + 1651200;
  p.ow1   = ws + 1716736;
  p.out   = (float*)d_out;

  mfn_persistent<<<NBATCH, 1024, 0, stream>>>(p);
}

// Round 5
// 87834.399 us; speedup vs baseline: 2.1092x; 2.1092x over previous
//
#include <hip/hip_runtime.h>
#include <math.h>

#define TSTEPS 512
#define NBATCH 256
#define DLL 300
#define DAA 74
#define DVV 35
#define DX  409
#define DH  128
#define DMEM 256
#define CST 768   // 6*DH

typedef unsigned short u16;
typedef unsigned int   u32;
typedef float v2f __attribute__((ext_vector_type(2)));

__device__ __forceinline__ float tobf(u16 w){ return __uint_as_float(((u32)w)<<16); }
__device__ __forceinline__ float sigf(float x){ return 1.0f/(1.0f+expf(-x)); }

// dst[k*OUT + o] = bf16(src[o*IN + k])   (transpose to [K][OUT] for coalesced GEMV)
__global__ void cast_transpose(const float* __restrict__ src, u16* __restrict__ dst,
                               int OUT, int IN){
  int idx = blockIdx.x*blockDim.x + threadIdx.x;
  int total = OUT*IN;
  if (idx >= total) return;
  int k = idx / OUT;
  int o = idx - k*OUT;
  float v = src[o*IN + k];
  u32 u = __float_as_uint(v);
  u32 r = (u + 0x7fffu + ((u>>16)&1u)) >> 16;   // RNE
  dst[idx] = (u16)r;
}

struct P {
  const float* x;
  const float *bih_l,*bhh_l,*bih_a,*bhh_a,*bih_v,*bhh_v;
  const float *a1b1,*a1b2,*a2b1,*a2b2,*g1b1,*g1b2,*g2b1,*g2b2;
  const float *ob1,*ow2,*ob2;
  const u16 *ihl,*hhl,*iha,*hha,*ihv,*hhv;
  const u16 *a1w1,*a1w2,*a2w1,*a2w2,*g1w1,*g1w2,*g2w1,*g2w2,*ow1;
  float* out;
};

// ROWS=2 rows per block, 512 threads, NO K-split: every weight matrix is swept
// front-to-back in lockstep by the whole block (the R1 access shape that gave
// ~100% L2 hit), each weight element feeding 2 FMA chains (row0,row1).
__global__ void __launch_bounds__(512)
mfn_persistent(P p){
  __shared__ __align__(16) float s_x2[818];     // [i][2] interleaved; L:0..299, A:300..373, V:374..408
  __shared__ __align__(16) float s_h2[3][256];  // [m][j*2+r]
  __shared__ __align__(16) float s_c2[3][256];
  __shared__ __align__(16) float s_g[3072];     // [m*1024 + col*2 + r]
  __shared__ __align__(16) float s_cstar[1536]; // [idx*2+r], idx<768
  __shared__ __align__(16) float s_z[512];      // [row*256+col]
  __shared__ __align__(16) float s_attm[2048];  // [row*1024 + (att 768 | mem 256)]
  __shared__ __align__(16) float s_z2[1536];    // [row*768 + (u|v1|v2)]
  __shared__ __align__(16) float s_mem[512];    // [row*256+col]
  __shared__ __align__(16) float s_last[1280];  // [row*640+j]
  __shared__ float s_red[8];

  const int tid = threadIdx.x;
  const int n0  = blockIdx.x*2;
  const int col = tid&255, row = tid>>8;

  // ---- bias preload (registers, once) ----
  const float bLg = p.bih_l[tid]+p.bhh_l[tid];
  const float bAg = p.bih_a[tid]+p.bhh_a[tid];
  const float bVg = p.bih_v[tid]+p.bhh_v[tid];
  const float b_z1 = p.a1b1[col];
  const float b_s0 = p.a1b2[col], b_s1 = p.a1b2[col+256], b_s2 = p.a1b2[col+512];
  const float b_u  = p.a2b1[col], b_v1 = p.g1b1[col], b_v2 = p.g2b1[col];
  const float b_ch = p.a2b2[col], b_g1 = p.g1b2[col], b_g2 = p.g2b2[col];

  // ---- init state + x(0) ----
  {
    float* sh = &s_h2[0][0];
    float* sc = &s_c2[0][0];
    for (int i=tid; i<768; i+=512){ sh[i]=0.f; sc[i]=0.f; }
    if (tid < 512) s_mem[tid]=0.f;
    for (int i2=tid; i2<818; i2+=512){
      int i=i2>>1, r=i2&1;
      s_x2[i2] = p.x[(size_t)(n0+r)*DX + i];
    }
  }
  __syncthreads();

  for (int t=0; t<TSTEPS; t++){
    // ================ phase 1: LSTM gate sweeps (col=tid, full K, lockstep) ================
    {
      float a0=0.f, a1=0.f;
      #pragma unroll 4
      for (int k=0;k<DLL;k++){ v2f xv=*(const v2f*)&s_x2[k*2]; float w=tobf(p.ihl[k*512+tid]); a0+=xv.x*w; a1+=xv.y*w; }
      #pragma unroll 4
      for (int k=0;k<DH;k++){ v2f hv=*(const v2f*)&s_h2[0][k*2]; float w=tobf(p.hhl[k*512+tid]); a0+=hv.x*w; a1+=hv.y*w; }
      s_g[tid*2]=a0+bLg; s_g[tid*2+1]=a1+bLg;
      a0=0.f; a1=0.f;
      #pragma unroll 4
      for (int k=0;k<DAA;k++){ v2f xv=*(const v2f*)&s_x2[(DLL+k)*2]; float w=tobf(p.iha[k*512+tid]); a0+=xv.x*w; a1+=xv.y*w; }
      #pragma unroll 4
      for (int k=0;k<DH;k++){ v2f hv=*(const v2f*)&s_h2[1][k*2]; float w=tobf(p.hha[k*512+tid]); a0+=hv.x*w; a1+=hv.y*w; }
      s_g[1024+tid*2]=a0+bAg; s_g[1024+tid*2+1]=a1+bAg;
      a0=0.f; a1=0.f;
      #pragma unroll 4
      for (int k=0;k<DVV;k++){ v2f xv=*(const v2f*)&s_x2[(DLL+DAA+k)*2]; float w=tobf(p.ihv[k*512+tid]); a0+=xv.x*w; a1+=xv.y*w; }
      #pragma unroll 4
      for (int k=0;k<DH;k++){ v2f hv=*(const v2f*)&s_h2[2][k*2]; float w=tobf(p.hhv[k*512+tid]); a0+=hv.x*w; a1+=hv.y*w; }
      s_g[2048+tid*2]=a0+bVg; s_g[2048+tid*2+1]=a1+bVg;
    }
    __syncthreads();                                   // B1

    // x(t+1) prefetch: issue now (s_x2 reads done), write at step end
    float xp0=0.f, xp1=0.f;
    if (t+1 < TSTEPS){
      const float* xb = p.x + (size_t)(t+1)*NBATCH*DX;
      xp0 = xb[(size_t)(n0+(tid&1))*DX + (tid>>1)];
      int i2 = tid+512;
      if (i2 < 818) xp1 = xb[(size_t)(n0+(i2&1))*DX + (i2>>1)];
    }

    // ================ phase 2: LSTM activations (768 tasks) ================
    for (int task=tid; task<768; task+=512){
      int m = task>>8, rem = task&255, u = rem>>1, r = rem&1;
      const float* gm = s_g + m*1024;
      float g0=gm[u*2+r], g1=gm[(128+u)*2+r], g2=gm[(256+u)*2+r], g3=gm[(384+u)*2+r];
      float ig=sigf(g0), fg=sigf(g1), gg=tanhf(g2), og=sigf(g3);
      float co = s_c2[m][u*2+r];
      float c  = fg*co + ig*gg;
      float h  = og*tanhf(c);
      s_c2[m][u*2+r]=c; s_h2[m][u*2+r]=h;
      int idx = m*128+u;
      s_cstar[idx*2+r]     = co;
      s_cstar[(384+idx)*2+r] = c;
    }
    __syncthreads();                                   // B2

    // ================ phase 3: att1_W1 (K=768 -> z1) ================
    {
      float acc=b_z1;
      #pragma unroll 4
      for (int k=0;k<CST;k++) acc += s_cstar[k*2+row]*tobf(p.a1w1[k*256+col]);
      s_z[row*256+col] = fmaxf(acc,0.f);
    }
    __syncthreads();                                   // B3

    // ================ phase 4: att1_W2 (K=256, 3 cols/thread) + softmax ================
    {
      float s0=b_s0, s1=b_s1, s2=b_s2;
      #pragma unroll 4
      for (int k=0;k<256;k++){
        float zv = s_z[row*256+k];
        const u16* wr = p.a1w2 + (size_t)k*768 + col;
        s0 += zv*tobf(wr[0]); s1 += zv*tobf(wr[256]); s2 += zv*tobf(wr[512]);
      }
      float mx = fmaxf(fmaxf(s0,s1),s2);
      for (int off=32; off; off>>=1) mx = fmaxf(mx, __shfl_down(mx, off));
      if ((tid&63)==0) s_red[tid>>6]=mx;
      __syncthreads();                                 // B4
      mx = fmaxf(fmaxf(s_red[row*4],s_red[row*4+1]), fmaxf(s_red[row*4+2],s_red[row*4+3]));
      float e0=expf(s0-mx), e1=expf(s1-mx), e2=expf(s2-mx);
      float ss = e0+e1+e2;
      for (int off=32; off; off>>=1) ss += __shfl_down(ss, off);
      __syncthreads();                                 // B5 (all max-reads done)
      if ((tid&63)==0) s_red[tid>>6]=ss;
      s_attm[row*1024 + 768 + col] = s_mem[row*256+col];   // mem copy into [att|mem]
      __syncthreads();                                 // B6
      float inv = 1.0f/(s_red[row*4]+s_red[row*4+1]+s_red[row*4+2]+s_red[row*4+3]);
      s_attm[row*1024 + col]       = e0*inv*s_cstar[col*2+row];
      s_attm[row*1024 + 256 + col] = e1*inv*s_cstar[(256+col)*2+row];
      s_attm[row*1024 + 512 + col] = e2*inv*s_cstar[(512+col)*2+row];
    }
    __syncthreads();                                   // B7

    // ================ phase 5: fused att2/g1/g2 layer-1 (full-K sweeps) ================
    {
      const float* ar = s_attm + row*1024;
      float au=b_u;
      #pragma unroll 4
      for (int k=0;k<CST;k++)  au  += ar[k]*tobf(p.a2w1[k*256+col]);
      float av1=b_v1;
      #pragma unroll 4
      for (int k=0;k<1024;k++) av1 += ar[k]*tobf(p.g1w1[k*256+col]);
      float av2=b_v2;
      #pragma unroll 4
      for (int k=0;k<1024;k++) av2 += ar[k]*tobf(p.g2w1[k*256+col]);
      s_z2[row*768 + col]       = fmaxf(au ,0.f);
      s_z2[row*768 + 256 + col] = fmaxf(av1,0.f);
      s_z2[row*768 + 512 + col] = fmaxf(av2,0.f);
    }
    __syncthreads();                                   // B8

    // ================ phase 6: layer-2s + mem update + x write ================
    {
      const float* zr = s_z2 + row*768;
      float ch=b_ch;
      #pragma unroll 4
      for (int k=0;k<256;k++) ch  += zr[k]      *tobf(p.a2w2[k*256+col]);
      float gm1=b_g1;
      #pragma unroll 4
      for (int k=0;k<256;k++) gm1 += zr[256+k]  *tobf(p.g1w2[k*256+col]);
      float gm2=b_g2;
      #pragma unroll 4
      for (int k=0;k<256;k++) gm2 += zr[512+k]  *tobf(p.g2w2[k*256+col]);
      float mo = s_mem[row*256+col];
      s_mem[row*256+col] = sigf(gm1)*mo + sigf(gm2)*tanhf(ch);
      if (t+1 < TSTEPS){
        s_x2[tid] = xp0;
        if (tid+512 < 818) s_x2[tid+512] = xp1;
      }
    }
    __syncthreads();                                   // B9
  }

  // ================ output MLP ================
  for (int i=tid; i<1280; i+=512){
    int r = (i>=640)?1:0, j = i-r*640;
    float v;
    if (j<384){ int m=j>>7, u=j&127; v=s_h2[m][u*2+r]; }
    else v = s_mem[r*256 + (j-384)];
    s_last[r*640+j]=v;
  }
  __syncthreads();
  {
    float acc = p.ob1[col];
    #pragma unroll 4
    for (int k=0;k<640;k++) acc += s_last[row*640+k]*tobf(p.ow1[k*256+col]);
    float pp = fmaxf(acc,0.f)*p.ow2[col];
    for (int off=32; off; off>>=1) pp += __shfl_down(pp, off);
    if ((tid&63)==0) s_red[tid>>6]=pp;
    __syncthreads();
    if ((tid&255)==0)
      p.out[n0+row] = s_red[row*4]+s_red[row*4+1]+s_red[row*4+2]+s_red[row*4+3] + p.ob2[0];
  }
}

extern "C" void kernel_launch(void* const* d_in, const int* in_sizes, int n_in,
                              void* d_out, int out_size, void* d_ws, size_t ws_size,
                              hipStream_t stream){
  u16* ws = (u16*)d_ws;
  struct M { int src; size_t off; int OUT, IN; };
  const M mats[15] = {
    { 5,       0, 512,  300},   // Wih_l
    { 6,  153600, 512,  128},   // Whh_l
    { 9,  219136, 512,   74},   // Wih_a
    {10,  257024, 512,  128},   // Whh_a
    {13,  322560, 512,   35},   // Wih_v
    {14,  340480, 512,  128},   // Whh_v
    {17,  406016, 256,  768},   // att1_W1
    {19,  602624, 768,  256},   // att1_W2
    {21,  799232, 256,  768},   // att2_W1
    {23,  995840, 256,  256},   // att2_W2
    {25, 1061376, 256, 1024},   // g1_W1
    {27, 1323520, 256,  256},   // g1_W2
    {29, 1389056, 256, 1024},   // g2_W1
    {31, 1651200, 256,  256},   // g2_W2
    {33, 1716736, 256,  640},   // out_W1
  };
  for (int i=0;i<15;i++){
    int total = mats[i].OUT*mats[i].IN;
    cast_transpose<<<(total+255)/256, 256, 0, stream>>>(
        (const float*)d_in[mats[i].src], ws + mats[i].off, mats[i].OUT, mats[i].IN);
  }

  P p;
  p.x     = (const float*)d_in[0];
  p.bih_l = (const float*)d_in[7];  p.bhh_l = (const float*)d_in[8];
  p.bih_a = (const float*)d_in[11]; p.bhh_a = (const float*)d_in[12];
  p.bih_v = (const float*)d_in[15]; p.bhh_v = (const float*)d_in[16];
  p.a1b1  = (const float*)d_in[18]; p.a1b2  = (const float*)d_in[20];
  p.a2b1  = (const float*)d_in[22]; p.a2b2  = (const float*)d_in[24];
  p.g1b1  = (const float*)d_in[26]; p.g1b2  = (const float*)d_in[28];
  p.g2b1  = (const float*)d_in[30]; p.g2b2  = (const float*)d_in[32];
  p.ob1   = (const float*)d_in[34]; p.ow2   = (const float*)d_in[35];
  p.ob2   = (const float*)d_in[36];
  p.ihl   = ws + 0;       p.hhl  = ws + 153600;
  p.iha   = ws + 219136;  p.hha  = ws + 257024;
  p.ihv   = ws + 322560;  p.hhv  = ws + 340480;
  p.a1w1  = ws + 406016;  p.a1w2 = ws + 602624;
  p.a2w1  = ws + 799232;  p.a2w2 = ws + 995840;
  p.g1w1  = ws + 1061376; p.g1w2 = ws + 1323520;
  p.g2w1  = ws + 1389056; p.g2w2 = ws + 1651200;
  p.ow1   = ws + 1716736;
  p.out   = (float*)d_out;

  mfn_persistent<<<NBATCH/2, 512, 0, stream>>>(p);
}